// Round 3
// baseline (978.167 us; speedup 1.0000x reference)
//
#include <hip/hip_runtime.h>

// ---------------- problem constants ----------------
#define N_NODES 32768
#define E_EDGES 524288
#define F_IN    215
#define H_DIM   256
#define T_TYPES 8
#define L_LAYERS 3
#define B_GRAPHS 32
#define MAXN_   1024
#define NT_BINS (N_NODES * T_TYPES)   // 262144

typedef float  f32x4  __attribute__((ext_vector_type(4)));
typedef __bf16 bf16x8 __attribute__((ext_vector_type(8)));

__device__ __forceinline__ unsigned short f2bf(float f) {
  union { float f; unsigned u; } v; v.f = f;
  unsigned r = v.u + 0x7fffu + ((v.u >> 16) & 1u);
  return (unsigned short)(r >> 16);
}
__device__ __forceinline__ float bf2f(unsigned short h) {
  union { unsigned u; float f; } v; v.u = ((unsigned)h) << 16;
  return v.f;
}

typedef const __attribute__((address_space(1))) unsigned int* gas_ptr;
typedef __attribute__((address_space(3))) unsigned int* las_ptr;
__device__ __forceinline__ void gload_lds16(const unsigned short* g, unsigned short* l) {
  __builtin_amdgcn_global_load_lds((gas_ptr)g, (las_ptr)l, 16, 0, 0);
}

// ---------------- ws layout (bytes) ----------------
// BIG region time-shared by liveness (stream order):
//   t0: counts(+0, 1MB) cursor(+1MB, 1MB) bsum(+2MB, 1KB)      [edge sort]
//   t1: xpad(+0, 16.8MB) wppad(+32MB, 131KB)                   [input proj]
//   t2 per layer: A' = S_flat (N,2048) bf16, 134.2MB           [dead after m-GEMM]
//   t3 per layer: gi(+0, 50.3MB) gh(+48MB, 50.3MB)             [dead after gru_gates]
//   t4: part(+0, 256KB)                                        [readout]
static constexpr size_t OFF_BIG     = 0;            // 134217728
static constexpr size_t REL_CURSOR  = 1048576;
static constexpr size_t REL_BSUM    = 2097152;
static constexpr size_t REL_WPPAD   = 33554432;
static constexpr size_t REL_GH      = 50331648;
static constexpr size_t OFF_H_B     = 134217728;    // 16777216   h bf16 (N,H)
static constexpr size_t OFF_M_B     = 150994944;    // 16777216   m bf16 (N,H)
static constexpr size_t OFF_WMB     = 167772160;    // 3145728    Wm reshaped bf16 (L,256,2048)
static constexpr size_t OFF_WIH     = 170917888;    // 1179648    Wih bf16
static constexpr size_t OFF_WHH     = 172097536;    // 1179648    Whh bf16
static constexpr size_t OFF_OFFS    = 173277184;    // 1048832    seg offsets (NT+1)
static constexpr size_t OFF_SORTED  = 174326016;    // 1048576    src as ushort, sorted by (dst*8+t)
static constexpr size_t OFF_CNT     = 175374592;    // 524288     cnt16 (N,T) ushort
static constexpr size_t WS_REQUIRED = 175898880;    // 175.9 MB <= proven-safe 176.16 MB

// ---------------- edge preprocessing: counting sort by key=(dst*8+type) ----------------
__global__ void hist_kernel(const int* __restrict__ dst, const int* __restrict__ et,
                            int* __restrict__ cnt) {
  int e = blockIdx.x * 256 + threadIdx.x;
  atomicAdd(&cnt[dst[e] * T_TYPES + et[e]], 1);
}

// hierarchical scan over NT_BINS: scan1 (block-local) -> scan2 (block sums) -> scan3 (add back)
__global__ __launch_bounds__(1024) void scan1(const int* __restrict__ cnt,
                                              int* __restrict__ offs,
                                              int* __restrict__ bsum) {
  __shared__ int wsum[16];
  const int t = threadIdx.x, lane = t & 63, wid = t >> 6;
  const int idx = blockIdx.x * 1024 + t;
  const int v = cnt[idx];
  int x = v;
  #pragma unroll
  for (int off = 1; off < 64; off <<= 1) {
    int u = __shfl_up(x, off, 64);
    if (lane >= off) x += u;
  }
  if (lane == 63) wsum[wid] = x;
  __syncthreads();
  int wbase = 0;
  for (int i = 0; i < wid; ++i) wbase += wsum[i];
  offs[idx] = wbase + x - v;                 // block-local exclusive
  if (t == 1023) bsum[blockIdx.x] = wbase + x;
}

__global__ __launch_bounds__(256) void scan2(int* __restrict__ bsum) {
  __shared__ int wsum[4];
  const int t = threadIdx.x, lane = t & 63, wid = t >> 6;
  const int v = bsum[t];
  int x = v;
  #pragma unroll
  for (int off = 1; off < 64; off <<= 1) {
    int u = __shfl_up(x, off, 64);
    if (lane >= off) x += u;
  }
  if (lane == 63) wsum[wid] = x;
  __syncthreads();
  int wbase = 0;
  for (int i = 0; i < wid; ++i) wbase += wsum[i];
  __syncthreads();
  bsum[t] = wbase + x - v;                   // exclusive
}

__global__ __launch_bounds__(1024) void scan3(int* __restrict__ offs,
                                              const int* __restrict__ bsum,
                                              int* __restrict__ cursor) {
  const int idx = blockIdx.x * 1024 + threadIdx.x;
  const int o = offs[idx] + bsum[blockIdx.x];
  offs[idx] = o;
  cursor[idx] = o;
  if (idx == 0) offs[NT_BINS] = E_EDGES;
}

__global__ void reorder_kernel(const int* __restrict__ src, const int* __restrict__ dst,
                               const int* __restrict__ et, int* __restrict__ cursor,
                               unsigned short* __restrict__ sorted) {
  int e = blockIdx.x * 256 + threadIdx.x;
  int key = dst[e] * T_TYPES + et[e];
  int p = atomicAdd(&cursor[key], 1);
  sorted[p] = (unsigned short)src[e];
}

// ---------------- conversions ----------------
__global__ void cvt_f32_bf16(const float* __restrict__ in, unsigned short* __restrict__ out, int n) {
  int i = blockIdx.x * 256 + threadIdx.x;
  if (i < n) out[i] = f2bf(in[i]);
}

__global__ void pad_cvt(const float* __restrict__ in, unsigned short* __restrict__ out,
                        int rows, int cin) {
  int i = blockIdx.x * 256 + threadIdx.x;
  if (i >= rows * 256) return;
  int r = i >> 8, c = i & 255;
  out[i] = (c < cin) ? f2bf(in[(size_t)r * cin + c]) : (unsigned short)0;
}

// Wm (L,T,H,H) fp32 -> Wcat (L, 256 rows j, 2048 cols = t*256+d) bf16
__global__ void reshape_wm(const float* __restrict__ Wm, unsigned short* __restrict__ out) {
  int i = blockIdx.x * 256 + threadIdx.x;   // over 3*256*2048
  int l = i >> 19;
  int r = (i >> 11) & 255;
  int c = i & 2047;
  int t = c >> 8, d = c & 255;
  out[i] = f2bf(Wm[(((size_t)(l * T_TYPES + t) * 256 + r) << 8) + d]);
}

// ---------------- GEMM: C(N x M) = A(N x K) @ W(M x K)^T (+bias), bf16 in/out ----------------
// 128x128 tile, BK=32, 4 waves, mfma_f32_16x16x32_bf16, global_load_lds width-16 staging.
__global__ __launch_bounds__(256, 2) void gemm_bt(
    const unsigned short* __restrict__ A,
    const unsigned short* __restrict__ W,
    const float* __restrict__ bias,
    unsigned short* __restrict__ C,
    int M, int K) {
  __shared__ unsigned short As[128 * 32];   // unpadded: exact lane-order for global_load_lds
  __shared__ unsigned short Bs[128 * 32];
  const int tid = threadIdx.x;
  const int lane = tid & 63;
  const int wv = tid >> 6;
  const int lrow = lane & 15;
  const int lquad = lane >> 4;
  const int bm0 = blockIdx.x * 128;
  const int bn0 = blockIdx.y * 128;
  const int srow = wv * 16 + (lane >> 2);   // staging row (i=0); +64 for i=1
  const int scol = (lane & 3) * 8;          // ushort col offset -> lds byte off = lane*16

  f32x4 acc[2][8] = {};

  for (int kt = 0; kt < K; kt += 32) {
    #pragma unroll
    for (int i = 0; i < 2; ++i) {
      const int row = srow + i * 64;
      gload_lds16(A + (size_t)(bm0 + row) * K + kt + scol, &As[row * 32 + scol]);
      gload_lds16(W + (size_t)(bn0 + row) * K + kt + scol, &Bs[row * 32 + scol]);
    }
    __syncthreads();
    bf16x8 af[2], bfr[8];
    #pragma unroll
    for (int mt = 0; mt < 2; ++mt)
      af[mt] = *(const bf16x8*)(&As[(wv * 32 + mt * 16 + lrow) * 32 + lquad * 8]);
    #pragma unroll
    for (int nt = 0; nt < 8; ++nt)
      bfr[nt] = *(const bf16x8*)(&Bs[(nt * 16 + lrow) * 32 + lquad * 8]);
    #pragma unroll
    for (int mt = 0; mt < 2; ++mt)
      #pragma unroll
      for (int nt = 0; nt < 8; ++nt)
        acc[mt][nt] = __builtin_amdgcn_mfma_f32_16x16x32_bf16(af[mt], bfr[nt], acc[mt][nt], 0, 0, 0);
    __syncthreads();
  }

  #pragma unroll
  for (int mt = 0; mt < 2; ++mt) {
    #pragma unroll
    for (int r = 0; r < 4; ++r) {
      const int grow = bm0 + wv * 32 + mt * 16 + lquad * 4 + r;
      #pragma unroll
      for (int nt = 0; nt < 8; ++nt) {
        const int gcol = bn0 + nt * 16 + lrow;
        float v = acc[mt][nt][r] + (bias ? bias[gcol] : 0.f);
        C[(size_t)grow * M + gcol] = f2bf(v);
      }
    }
  }
}

// ---------------- S build: one wave per (dst,type); S[dst,t,:] = sum h[src] ----------------
__global__ __launch_bounds__(256) void build_S(
    const int* __restrict__ offs, const unsigned short* __restrict__ sorted,
    const unsigned short* __restrict__ hb, unsigned short* __restrict__ Ap,
    unsigned short* __restrict__ cnt16) {
  const int lane = threadIdx.x & 63;
  const int wv = threadIdx.x >> 6;
  const int key = blockIdx.x * 4 + wv;          // dst*8 + t
  const int beg = offs[key], end = offs[key + 1];
  float a0 = 0.f, a1 = 0.f, a2 = 0.f, a3 = 0.f;
  for (int e = beg; e < end; ++e) {
    const int s = sorted[e];
    const ushort4 v = *(const ushort4*)(hb + (size_t)s * H_DIM + lane * 4);
    a0 += bf2f(v.x); a1 += bf2f(v.y); a2 += bf2f(v.z); a3 += bf2f(v.w);
  }
  ushort4 o;
  o.x = f2bf(a0); o.y = f2bf(a1); o.z = f2bf(a2); o.w = f2bf(a3);
  *(ushort4*)(Ap + (size_t)key * H_DIM + lane * 4) = o;   // key*256 == dst*2048 + t*256
  if (lane == 0) cnt16[key] = (unsigned short)(end - beg);
}

// ---------------- m += sum_t cnt[dst,t] * bm[l,t,:] (exact bias) ----------------
__global__ __launch_bounds__(256) void madd_bias(
    unsigned short* __restrict__ m, const unsigned short* __restrict__ cnt16,
    const float* __restrict__ bm_l) {
  const int i = blockIdx.x * 256 + threadIdx.x;  // over N*H, one block per node
  const int n = i >> 8;
  const int j = i & 255;
  float acc = bf2f(m[i]);
  #pragma unroll
  for (int t = 0; t < T_TYPES; ++t)
    acc += (float)cnt16[n * T_TYPES + t] * bm_l[t * H_DIM + j];
  m[i] = f2bf(acc);
}

// ---------------- GRU gates (elementwise, bf16 h in-place) ----------------
__global__ __launch_bounds__(256) void gru_gates(
    const unsigned short* __restrict__ gi, const unsigned short* __restrict__ gh,
    unsigned short* __restrict__ hb) {
  const int i = blockIdx.x * 256 + threadIdx.x;
  const int n = i >> 8;
  const int c = i & 255;
  const size_t b3 = (size_t)n * 768;
  const float ir = bf2f(gi[b3 + c]);
  const float iz = bf2f(gi[b3 + 256 + c]);
  const float in_ = bf2f(gi[b3 + 512 + c]);
  const float hr = bf2f(gh[b3 + c]);
  const float hz = bf2f(gh[b3 + 256 + c]);
  const float hn = bf2f(gh[b3 + 512 + c]);
  const float r = 1.f / (1.f + __expf(-(ir + hr)));
  const float z = 1.f / (1.f + __expf(-(iz + hz)));
  const float nn = tanhf(in_ + r * hn);
  const float hprev = bf2f(hb[i]);
  hb[i] = f2bf((1.f - z) * nn + z * hprev);
}

// ---------------- readout ----------------
__global__ __launch_bounds__(256) void readout_partial(const unsigned short* __restrict__ hb,
                                                       float* __restrict__ part) {
  const int b = blockIdx.x >> 3;
  const int ch = blockIdx.x & 7;
  const int c = threadIdx.x;
  const unsigned short* base = hb + ((size_t)b * MAXN_ + ch * 128) * H_DIM + c;
  float s = 0.f;
  #pragma unroll 4
  for (int i = 0; i < 128; ++i) s += bf2f(base[(size_t)i * H_DIM]);
  part[(size_t)blockIdx.x * H_DIM + c] = s;
}

__global__ __launch_bounds__(256) void readout_final(const float* __restrict__ part,
                                                     float* __restrict__ out) {
  const int b = blockIdx.x;
  const int c = threadIdx.x;
  float s = 0.f;
  #pragma unroll
  for (int i = 0; i < 8; ++i) s += part[((size_t)b * 8 + i) * H_DIM + c];
  out[b * H_DIM + c] = s;
}

// ---------------- launch ----------------
extern "C" void kernel_launch(void* const* d_in, const int* in_sizes, int n_in,
                              void* d_out, int out_size, void* d_ws, size_t ws_size,
                              hipStream_t stream) {
  if (ws_size < WS_REQUIRED) return;  // diagnostic no-op guard

  const float* X   = (const float*)d_in[0];
  const int*   ei  = (const int*)d_in[1];
  const int*   et  = (const int*)d_in[2];
  const float* Wp  = (const float*)d_in[3];
  const float* bp  = (const float*)d_in[4];
  const float* Wm  = (const float*)d_in[5];
  const float* bm  = (const float*)d_in[6];
  const float* Wih = (const float*)d_in[7];
  const float* Whh = (const float*)d_in[8];
  const float* bih = (const float*)d_in[9];
  const float* bhh = (const float*)d_in[10];
  float* out = (float*)d_out;
  char* ws = (char*)d_ws;

  // BIG aliases (stream-ordered liveness)
  int*            counts = (int*)(ws + OFF_BIG);
  int*            cursor = (int*)(ws + OFF_BIG + REL_CURSOR);
  int*            bsum   = (int*)(ws + OFF_BIG + REL_BSUM);
  unsigned short* xpad   = (unsigned short*)(ws + OFF_BIG);
  unsigned short* wppad  = (unsigned short*)(ws + OFF_BIG + REL_WPPAD);
  unsigned short* Ap     = (unsigned short*)(ws + OFF_BIG);            // S_flat (N,2048)
  unsigned short* gi     = (unsigned short*)(ws + OFF_BIG);
  unsigned short* gh     = (unsigned short*)(ws + OFF_BIG + REL_GH);
  float*          part   = (float*)(ws + OFF_BIG);
  // persistent
  unsigned short* h_b    = (unsigned short*)(ws + OFF_H_B);
  unsigned short* m_b    = (unsigned short*)(ws + OFF_M_B);
  unsigned short* wmb    = (unsigned short*)(ws + OFF_WMB);
  unsigned short* wih_b  = (unsigned short*)(ws + OFF_WIH);
  unsigned short* whh_b  = (unsigned short*)(ws + OFF_WHH);
  int*            offs   = (int*)(ws + OFF_OFFS);
  unsigned short* sorted = (unsigned short*)(ws + OFF_SORTED);
  unsigned short* cnt16  = (unsigned short*)(ws + OFF_CNT);

  const int* src = ei;
  const int* dst = ei + E_EDGES;

  // ---- counting sort of edges by (dst*8 + type), once (shared by all layers) ----
  hipMemsetAsync(counts, 0, NT_BINS * sizeof(int), stream);
  hist_kernel<<<E_EDGES / 256, 256, 0, stream>>>(dst, et, counts);
  scan1<<<NT_BINS / 1024, 1024, 0, stream>>>(counts, offs, bsum);
  scan2<<<1, 256, 0, stream>>>(bsum);
  scan3<<<NT_BINS / 1024, 1024, 0, stream>>>(offs, bsum, cursor);
  reorder_kernel<<<E_EDGES / 256, 256, 0, stream>>>(src, dst, et, cursor, sorted);

  // ---- weight/input conversion to bf16 (xpad/wppad alias BIG after sort is done) ----
  pad_cvt<<<(N_NODES * 256) / 256, 256, 0, stream>>>(X, xpad, N_NODES, F_IN);
  pad_cvt<<<(256 * 256) / 256, 256, 0, stream>>>(Wp, wppad, 256, F_IN);
  reshape_wm<<<(L_LAYERS * 256 * 2048) / 256, 256, 0, stream>>>(Wm, wmb);
  cvt_f32_bf16<<<(L_LAYERS * 3 * H_DIM * H_DIM) / 256, 256, 0, stream>>>(Wih, wih_b, L_LAYERS * 3 * H_DIM * H_DIM);
  cvt_f32_bf16<<<(L_LAYERS * 3 * H_DIM * H_DIM) / 256, 256, 0, stream>>>(Whh, whh_b, L_LAYERS * 3 * H_DIM * H_DIM);

  // ---- input projection: h = X @ Wp^T + bp ----
  gemm_bt<<<dim3(N_NODES / 128, 2), 256, 0, stream>>>(xpad, wppad, bp, h_b, H_DIM, 256);

  for (int l = 0; l < L_LAYERS; ++l) {
    const unsigned short* wm_l  = wmb + (size_t)l * 256 * 2048;
    const unsigned short* wih_l = wih_b + (size_t)l * 3 * H_DIM * H_DIM;
    const unsigned short* whh_l = whh_b + (size_t)l * 3 * H_DIM * H_DIM;
    const float* bm_l  = bm + (size_t)l * T_TYPES * H_DIM;
    const float* bih_l = bih + (size_t)l * 3 * H_DIM;
    const float* bhh_l = bhh + (size_t)l * 3 * H_DIM;

    // S[dst,t,:] = sum_{e:(dst,t)} h[src]   (gather from 16.8 MB h: L2/LLC-resident)
    build_S<<<NT_BINS / 4, 256, 0, stream>>>(offs, sorted, h_b, Ap, cnt16);
    // m = S_flat @ Wcat^T  (K=2048; bias folded separately)
    gemm_bt<<<dim3(N_NODES / 128, 2), 256, 0, stream>>>(Ap, wm_l, nullptr, m_b, H_DIM, 2048);
    // m += sum_t cnt[dst,t]*bm[l,t,:]
    madd_bias<<<(N_NODES * H_DIM) / 256, 256, 0, stream>>>(m_b, cnt16, bm_l);
    // gi = m @ Wih^T + bih ; gh = h @ Whh^T + bhh   (gi/gh alias A' region - dead now)
    gemm_bt<<<dim3(N_NODES / 128, 6), 256, 0, stream>>>(m_b, wih_l, bih_l, gi, 768, 256);
    gemm_bt<<<dim3(N_NODES / 128, 6), 256, 0, stream>>>(h_b, whh_l, bhh_l, gh, 768, 256);
    // gate math, in-place bf16 h update
    gru_gates<<<(N_NODES * H_DIM) / 256, 256, 0, stream>>>(gi, gh, h_b);
  }

  readout_partial<<<B_GRAPHS * 8, 256, 0, stream>>>(h_b, part);
  readout_final<<<B_GRAPHS, 256, 0, stream>>>(part, out);

  (void)in_sizes; (void)n_in; (void)out_size;
}

// Round 4
// 912.772 us; speedup vs baseline: 1.0716x; 1.0716x over previous
//
#include <hip/hip_runtime.h>

// ---------------- problem constants ----------------
#define N_NODES 32768
#define E_EDGES 524288
#define F_IN    215
#define H_DIM   256
#define T_TYPES 8
#define L_LAYERS 3
#define B_GRAPHS 32
#define MAXN_   1024
#define NT_BINS (N_NODES * T_TYPES)   // 262144

typedef float  f32x4  __attribute__((ext_vector_type(4)));
typedef __bf16 bf16x8 __attribute__((ext_vector_type(8)));

__device__ __forceinline__ unsigned short f2bf(float f) {
  union { float f; unsigned u; } v; v.f = f;
  unsigned r = v.u + 0x7fffu + ((v.u >> 16) & 1u);
  return (unsigned short)(r >> 16);
}
__device__ __forceinline__ float bf2f(unsigned short h) {
  union { unsigned u; float f; } v; v.u = ((unsigned)h) << 16;
  return v.f;
}
__device__ __forceinline__ float bflo(unsigned u) { union { unsigned x; float f; } v; v.x = u << 16; return v.f; }
__device__ __forceinline__ float bfhi(unsigned u) { union { unsigned x; float f; } v; v.x = u & 0xffff0000u; return v.f; }

typedef const __attribute__((address_space(1))) unsigned int* gas_ptr;
typedef __attribute__((address_space(3))) unsigned int* las_ptr;
__device__ __forceinline__ void gload_lds16(const unsigned short* g, unsigned short* l) {
  __builtin_amdgcn_global_load_lds((gas_ptr)g, (las_ptr)l, 16, 0, 0);
}

// ---------------- ws layout (bytes) ----------------
// BIG region time-shared by liveness (stream order):
//   t0: counts(+0, 1MB) cursor(+1MB, 1MB) bsum(+2MB, 1KB)      [edge sort]
//   t1: xpad(+0, 16.8MB) wppad(+32MB, 131KB)                   [input proj]
//   t2 per layer: gi(+0, 50.3MB) gh(+48MB, 50.3MB)             [dead after gru_gates]
//   t3: part(+0, 256KB)                                        [readout]
static constexpr size_t OFF_BIG     = 0;            // 134217728
static constexpr size_t REL_CURSOR  = 1048576;
static constexpr size_t REL_BSUM    = 2097152;
static constexpr size_t REL_WPPAD   = 33554432;
static constexpr size_t REL_GH      = 50331648;
static constexpr size_t OFF_H_B     = 134217728;    // 16777216   h bf16 (N,H)
static constexpr size_t OFF_M_B     = 150994944;    // 16777216   m bf16 (N,H)
static constexpr size_t OFF_WMB     = 167772160;    // 3145728    Wm bf16 (L,T,H,H) natural
static constexpr size_t OFF_WIH     = 170917888;    // 1179648    Wih bf16
static constexpr size_t OFF_WHH     = 172097536;    // 1179648    Whh bf16
static constexpr size_t OFF_OFFS    = 173277184;    // 1048832    seg offsets (NT+1)
static constexpr size_t OFF_SORTED  = 174326016;    // 1048576    src as ushort, sorted by (dst*8+t)
static constexpr size_t OFF_CNT     = 175374592;    // 524288     cnt16 (N,T) ushort
static constexpr size_t WS_REQUIRED = 175898880;    // 175.9 MB (proven safe)

// ---------------- edge preprocessing: counting sort by key=(dst*8+type) ----------------
__global__ void hist_kernel(const int* __restrict__ dst, const int* __restrict__ et,
                            int* __restrict__ cnt) {
  int e = blockIdx.x * 256 + threadIdx.x;
  atomicAdd(&cnt[dst[e] * T_TYPES + et[e]], 1);
}

__global__ void cvt_cnt16(const int* __restrict__ counts, unsigned short* __restrict__ c16) {
  int i = blockIdx.x * 256 + threadIdx.x;
  c16[i] = (unsigned short)counts[i];
}

__global__ __launch_bounds__(1024) void scan1(const int* __restrict__ cnt,
                                              int* __restrict__ offs,
                                              int* __restrict__ bsum) {
  __shared__ int wsum[16];
  const int t = threadIdx.x, lane = t & 63, wid = t >> 6;
  const int idx = blockIdx.x * 1024 + t;
  const int v = cnt[idx];
  int x = v;
  #pragma unroll
  for (int off = 1; off < 64; off <<= 1) {
    int u = __shfl_up(x, off, 64);
    if (lane >= off) x += u;
  }
  if (lane == 63) wsum[wid] = x;
  __syncthreads();
  int wbase = 0;
  for (int i = 0; i < wid; ++i) wbase += wsum[i];
  offs[idx] = wbase + x - v;
  if (t == 1023) bsum[blockIdx.x] = wbase + x;
}

__global__ __launch_bounds__(256) void scan2(int* __restrict__ bsum) {
  __shared__ int wsum[4];
  const int t = threadIdx.x, lane = t & 63, wid = t >> 6;
  const int v = bsum[t];
  int x = v;
  #pragma unroll
  for (int off = 1; off < 64; off <<= 1) {
    int u = __shfl_up(x, off, 64);
    if (lane >= off) x += u;
  }
  if (lane == 63) wsum[wid] = x;
  __syncthreads();
  int wbase = 0;
  for (int i = 0; i < wid; ++i) wbase += wsum[i];
  __syncthreads();
  bsum[t] = wbase + x - v;
}

__global__ __launch_bounds__(1024) void scan3(int* __restrict__ offs,
                                              const int* __restrict__ bsum,
                                              int* __restrict__ cursor) {
  const int idx = blockIdx.x * 1024 + threadIdx.x;
  const int o = offs[idx] + bsum[blockIdx.x];
  offs[idx] = o;
  cursor[idx] = o;
  if (idx == 0) offs[NT_BINS] = E_EDGES;
}

__global__ void reorder_kernel(const int* __restrict__ src, const int* __restrict__ dst,
                               const int* __restrict__ et, int* __restrict__ cursor,
                               unsigned short* __restrict__ sorted) {
  int e = blockIdx.x * 256 + threadIdx.x;
  int key = dst[e] * T_TYPES + et[e];
  int p = atomicAdd(&cursor[key], 1);
  sorted[p] = (unsigned short)src[e];
}

// ---------------- conversions ----------------
__global__ void cvt_f32_bf16(const float* __restrict__ in, unsigned short* __restrict__ out, int n) {
  int i = blockIdx.x * 256 + threadIdx.x;
  if (i < n) out[i] = f2bf(in[i]);
}

__global__ void pad_cvt(const float* __restrict__ in, unsigned short* __restrict__ out,
                        int rows, int cin) {
  int i = blockIdx.x * 256 + threadIdx.x;
  if (i >= rows * 256) return;
  int r = i >> 8, c = i & 255;
  out[i] = (c < cin) ? f2bf(in[(size_t)r * cin + c]) : (unsigned short)0;
}

// ---------------- GEMM: C(N x M) = A(N x K) @ W(M x K)^T (+bias), bf16 in/out ----------------
__global__ __launch_bounds__(256, 2) void gemm_bt(
    const unsigned short* __restrict__ A,
    const unsigned short* __restrict__ W,
    const float* __restrict__ bias,
    unsigned short* __restrict__ C,
    int M, int K) {
  __shared__ unsigned short As[128 * 32];
  __shared__ unsigned short Bs[128 * 32];
  const int tid = threadIdx.x;
  const int lane = tid & 63;
  const int wv = tid >> 6;
  const int lrow = lane & 15;
  const int lquad = lane >> 4;
  const int bm0 = blockIdx.x * 128;
  const int bn0 = blockIdx.y * 128;
  const int srow = wv * 16 + (lane >> 2);
  const int scol = (lane & 3) * 8;

  f32x4 acc[2][8] = {};

  for (int kt = 0; kt < K; kt += 32) {
    #pragma unroll
    for (int i = 0; i < 2; ++i) {
      const int row = srow + i * 64;
      gload_lds16(A + (size_t)(bm0 + row) * K + kt + scol, &As[row * 32 + scol]);
      gload_lds16(W + (size_t)(bn0 + row) * K + kt + scol, &Bs[row * 32 + scol]);
    }
    __syncthreads();
    bf16x8 af[2], bfr[8];
    #pragma unroll
    for (int mt = 0; mt < 2; ++mt)
      af[mt] = *(const bf16x8*)(&As[(wv * 32 + mt * 16 + lrow) * 32 + lquad * 8]);
    #pragma unroll
    for (int nt = 0; nt < 8; ++nt)
      bfr[nt] = *(const bf16x8*)(&Bs[(nt * 16 + lrow) * 32 + lquad * 8]);
    #pragma unroll
    for (int mt = 0; mt < 2; ++mt)
      #pragma unroll
      for (int nt = 0; nt < 8; ++nt)
        acc[mt][nt] = __builtin_amdgcn_mfma_f32_16x16x32_bf16(af[mt], bfr[nt], acc[mt][nt], 0, 0, 0);
    __syncthreads();
  }

  #pragma unroll
  for (int mt = 0; mt < 2; ++mt) {
    #pragma unroll
    for (int r = 0; r < 4; ++r) {
      const int grow = bm0 + wv * 32 + mt * 16 + lquad * 4 + r;
      #pragma unroll
      for (int nt = 0; nt < 8; ++nt) {
        const int gcol = bn0 + nt * 16 + lrow;
        float v = acc[mt][nt][r] + (bias ? bias[gcol] : 0.f);
        C[(size_t)grow * M + gcol] = f2bf(v);
      }
    }
  }
}

// ---------------- fused message GEMM ----------------
// Per block: 64 dsts, full 256 m-cols. For t=0..7: gather-sum h rows into LDS
// S_t tile (64x256 as 8 K-chunks, stride-40 padded), then 8 MFMA K-steps vs
// Wm[l,t] (natural (e,d) layout) staged via global_load_lds. Epilogue folds
// bias sum_t cnt[dst,t]*bm[t,:] and writes m bf16. S never touches HBM.
__global__ __launch_bounds__(256, 2) void msg_gemm(
    const int* __restrict__ offs, const unsigned short* __restrict__ sorted,
    const unsigned short* __restrict__ hb, const unsigned short* __restrict__ Wt_l,
    const unsigned short* __restrict__ cnt16, const float* __restrict__ bm_l,
    unsigned short* __restrict__ m) {
  __shared__ unsigned short Ss[8 * 64 * 40];   // 40 KB: chunk kc: [64 dst][40 (32 used)]
  __shared__ unsigned short Bs[256 * 32];      // 16 KB; reused as float bmS[2048] in epilogue
  const int tid = threadIdx.x;
  const int lane = tid & 63;
  const int wv = tid >> 6;
  const int lrow = lane & 15;     // also gather lane-in-group (16 cols x 16 lanes)
  const int lquad = lane >> 4;    // also gather group (4 concurrent dsts)
  const int bm0 = blockIdx.x * 64;
  const int srow = wv * 16 + (lane >> 2);
  const int scol = (lane & 3) * 8;

  f32x4 acc[16] = {};

  for (int t = 0; t < T_TYPES; ++t) {
    // ---- phase A: build S_t into LDS ----
    #pragma unroll
    for (int step = 0; step < 4; ++step) {
      const int dloc = wv * 16 + step * 4 + lquad;
      const int bin = (bm0 + dloc) * T_TYPES + t;
      const int beg = offs[bin], end = offs[bin + 1];
      float a[16];
      #pragma unroll
      for (int j = 0; j < 16; ++j) a[j] = 0.f;
      for (int e = beg; e < end; ++e) {
        const int s = sorted[e];
        const unsigned short* hp = hb + (size_t)s * H_DIM + lrow * 16;
        const uint4 v = *(const uint4*)hp;
        const uint4 w = *(const uint4*)(hp + 8);
        a[0]  += bflo(v.x); a[1]  += bfhi(v.x);
        a[2]  += bflo(v.y); a[3]  += bfhi(v.y);
        a[4]  += bflo(v.z); a[5]  += bfhi(v.z);
        a[6]  += bflo(v.w); a[7]  += bfhi(v.w);
        a[8]  += bflo(w.x); a[9]  += bfhi(w.x);
        a[10] += bflo(w.y); a[11] += bfhi(w.y);
        a[12] += bflo(w.z); a[13] += bfhi(w.z);
        a[14] += bflo(w.w); a[15] += bfhi(w.w);
      }
      // lane covers h-cols [lrow*16, lrow*16+16) -> chunk kc = lrow>>1, in-chunk base (lrow&1)*16
      union { unsigned short us[16]; uint4 q[2]; } ob;
      #pragma unroll
      for (int j = 0; j < 16; ++j) ob.us[j] = f2bf(a[j]);
      uint4* p = (uint4*)&Ss[(lrow >> 1) * 2560 + dloc * 40 + (lrow & 1) * 16];
      p[0] = ob.q[0];
      p[1] = ob.q[1];
    }
    __syncthreads();
    // ---- phase B: acc += S_t @ Wm[t]^T ----
    const unsigned short* Wt = Wt_l + (size_t)t * 256 * 256;
    for (int kc = 0; kc < 8; ++kc) {
      #pragma unroll
      for (int i = 0; i < 4; ++i) {
        const int j = srow + i * 64;
        gload_lds16(Wt + (size_t)j * 256 + kc * 32 + scol, &Bs[j * 32 + scol]);
      }
      __syncthreads();
      const bf16x8 af = *(const bf16x8*)(&Ss[kc * 2560 + (wv * 16 + lrow) * 40 + lquad * 8]);
      #pragma unroll
      for (int nt = 0; nt < 16; ++nt) {
        const bf16x8 bfr = *(const bf16x8*)(&Bs[(nt * 16 + lrow) * 32 + lquad * 8]);
        acc[nt] = __builtin_amdgcn_mfma_f32_16x16x32_bf16(af, bfr, acc[nt], 0, 0, 0);
      }
      __syncthreads();
    }
  }

  // ---- epilogue: m = acc + sum_t cnt[dst,t]*bm[t,:] ----
  float* bmS = (float*)Bs;   // 2048 floats (8 KB) - Bs is dead (last barrier passed)
  for (int i = tid; i < T_TYPES * H_DIM; i += 256) bmS[i] = bm_l[i];
  __syncthreads();
  float cnt[4][8];
  #pragma unroll
  for (int r = 0; r < 4; ++r) {
    const int grow = bm0 + wv * 16 + lquad * 4 + r;
    const uint4 cv = *(const uint4*)(cnt16 + (size_t)grow * T_TYPES);
    cnt[r][0] = (float)(cv.x & 0xffff); cnt[r][1] = (float)(cv.x >> 16);
    cnt[r][2] = (float)(cv.y & 0xffff); cnt[r][3] = (float)(cv.y >> 16);
    cnt[r][4] = (float)(cv.z & 0xffff); cnt[r][5] = (float)(cv.z >> 16);
    cnt[r][6] = (float)(cv.w & 0xffff); cnt[r][7] = (float)(cv.w >> 16);
  }
  #pragma unroll
  for (int nt = 0; nt < 16; ++nt) {
    const int gcol = nt * 16 + lrow;
    float bmv[8];
    #pragma unroll
    for (int t = 0; t < 8; ++t) bmv[t] = bmS[t * H_DIM + gcol];
    #pragma unroll
    for (int r = 0; r < 4; ++r) {
      const int grow = bm0 + wv * 16 + lquad * 4 + r;
      float v = acc[nt][r];
      #pragma unroll
      for (int t = 0; t < 8; ++t) v += cnt[r][t] * bmv[t];
      m[(size_t)grow * H_DIM + gcol] = f2bf(v);
    }
  }
}

// ---------------- GRU gates (elementwise, bf16 h in-place) ----------------
__global__ __launch_bounds__(256) void gru_gates(
    const unsigned short* __restrict__ gi, const unsigned short* __restrict__ gh,
    unsigned short* __restrict__ hb) {
  const int i = blockIdx.x * 256 + threadIdx.x;
  const int n = i >> 8;
  const int c = i & 255;
  const size_t b3 = (size_t)n * 768;
  const float ir = bf2f(gi[b3 + c]);
  const float iz = bf2f(gi[b3 + 256 + c]);
  const float in_ = bf2f(gi[b3 + 512 + c]);
  const float hr = bf2f(gh[b3 + c]);
  const float hz = bf2f(gh[b3 + 256 + c]);
  const float hn = bf2f(gh[b3 + 512 + c]);
  const float r = 1.f / (1.f + __expf(-(ir + hr)));
  const float z = 1.f / (1.f + __expf(-(iz + hz)));
  const float nn = tanhf(in_ + r * hn);
  const float hprev = bf2f(hb[i]);
  hb[i] = f2bf((1.f - z) * nn + z * hprev);
}

// ---------------- readout ----------------
__global__ __launch_bounds__(256) void readout_partial(const unsigned short* __restrict__ hb,
                                                       float* __restrict__ part) {
  const int b = blockIdx.x >> 3;
  const int ch = blockIdx.x & 7;
  const int c = threadIdx.x;
  const unsigned short* base = hb + ((size_t)b * MAXN_ + ch * 128) * H_DIM + c;
  float s = 0.f;
  #pragma unroll 4
  for (int i = 0; i < 128; ++i) s += bf2f(base[(size_t)i * H_DIM]);
  part[(size_t)blockIdx.x * H_DIM + c] = s;
}

__global__ __launch_bounds__(256) void readout_final(const float* __restrict__ part,
                                                     float* __restrict__ out) {
  const int b = blockIdx.x;
  const int c = threadIdx.x;
  float s = 0.f;
  #pragma unroll
  for (int i = 0; i < 8; ++i) s += part[((size_t)b * 8 + i) * H_DIM + c];
  out[b * H_DIM + c] = s;
}

// ---------------- launch ----------------
extern "C" void kernel_launch(void* const* d_in, const int* in_sizes, int n_in,
                              void* d_out, int out_size, void* d_ws, size_t ws_size,
                              hipStream_t stream) {
  if (ws_size < WS_REQUIRED) return;  // diagnostic no-op guard

  const float* X   = (const float*)d_in[0];
  const int*   ei  = (const int*)d_in[1];
  const int*   et  = (const int*)d_in[2];
  const float* Wp  = (const float*)d_in[3];
  const float* bp  = (const float*)d_in[4];
  const float* Wm  = (const float*)d_in[5];
  const float* bm  = (const float*)d_in[6];
  const float* Wih = (const float*)d_in[7];
  const float* Whh = (const float*)d_in[8];
  const float* bih = (const float*)d_in[9];
  const float* bhh = (const float*)d_in[10];
  float* out = (float*)d_out;
  char* ws = (char*)d_ws;

  // BIG aliases (stream-ordered liveness)
  int*            counts = (int*)(ws + OFF_BIG);
  int*            cursor = (int*)(ws + OFF_BIG + REL_CURSOR);
  int*            bsum   = (int*)(ws + OFF_BIG + REL_BSUM);
  unsigned short* xpad   = (unsigned short*)(ws + OFF_BIG);
  unsigned short* wppad  = (unsigned short*)(ws + OFF_BIG + REL_WPPAD);
  unsigned short* gi     = (unsigned short*)(ws + OFF_BIG);
  unsigned short* gh     = (unsigned short*)(ws + OFF_BIG + REL_GH);
  float*          part   = (float*)(ws + OFF_BIG);
  // persistent
  unsigned short* h_b    = (unsigned short*)(ws + OFF_H_B);
  unsigned short* m_b    = (unsigned short*)(ws + OFF_M_B);
  unsigned short* wmb    = (unsigned short*)(ws + OFF_WMB);
  unsigned short* wih_b  = (unsigned short*)(ws + OFF_WIH);
  unsigned short* whh_b  = (unsigned short*)(ws + OFF_WHH);
  int*            offs   = (int*)(ws + OFF_OFFS);
  unsigned short* sorted = (unsigned short*)(ws + OFF_SORTED);
  unsigned short* cnt16  = (unsigned short*)(ws + OFF_CNT);

  const int* src = ei;
  const int* dst = ei + E_EDGES;

  // ---- counting sort of edges by (dst*8 + type), once ----
  hipMemsetAsync(counts, 0, NT_BINS * sizeof(int), stream);
  hist_kernel<<<E_EDGES / 256, 256, 0, stream>>>(dst, et, counts);
  cvt_cnt16<<<NT_BINS / 256, 256, 0, stream>>>(counts, cnt16);  // before BIG reuse
  scan1<<<NT_BINS / 1024, 1024, 0, stream>>>(counts, offs, bsum);
  scan2<<<1, 256, 0, stream>>>(bsum);
  scan3<<<NT_BINS / 1024, 1024, 0, stream>>>(offs, bsum, cursor);
  reorder_kernel<<<E_EDGES / 256, 256, 0, stream>>>(src, dst, et, cursor, sorted);

  // ---- weight/input conversion to bf16 ----
  pad_cvt<<<(N_NODES * 256) / 256, 256, 0, stream>>>(X, xpad, N_NODES, F_IN);
  pad_cvt<<<(256 * 256) / 256, 256, 0, stream>>>(Wp, wppad, 256, F_IN);
  cvt_f32_bf16<<<(L_LAYERS * T_TYPES * H_DIM * H_DIM) / 256, 256, 0, stream>>>(
      Wm, wmb, L_LAYERS * T_TYPES * H_DIM * H_DIM);
  cvt_f32_bf16<<<(L_LAYERS * 3 * H_DIM * H_DIM) / 256, 256, 0, stream>>>(Wih, wih_b, L_LAYERS * 3 * H_DIM * H_DIM);
  cvt_f32_bf16<<<(L_LAYERS * 3 * H_DIM * H_DIM) / 256, 256, 0, stream>>>(Whh, whh_b, L_LAYERS * 3 * H_DIM * H_DIM);

  // ---- input projection: h = X @ Wp^T + bp ----
  gemm_bt<<<dim3(N_NODES / 128, 2), 256, 0, stream>>>(xpad, wppad, bp, h_b, H_DIM, 256);

  for (int l = 0; l < L_LAYERS; ++l) {
    const unsigned short* wm_l  = wmb + (size_t)l * T_TYPES * H_DIM * H_DIM;
    const unsigned short* wih_l = wih_b + (size_t)l * 3 * H_DIM * H_DIM;
    const unsigned short* whh_l = whh_b + (size_t)l * 3 * H_DIM * H_DIM;
    const float* bm_l  = bm + (size_t)l * T_TYPES * H_DIM;
    const float* bih_l = bih + (size_t)l * 3 * H_DIM;
    const float* bhh_l = bhh + (size_t)l * 3 * H_DIM;

    // fused: m = (scatter-sum_t h) @ Wm^T + cnt-weighted bm  (S stays in LDS)
    msg_gemm<<<N_NODES / 64, 256, 0, stream>>>(offs, sorted, h_b, wm_l, cnt16, bm_l, m_b);
    // gi = m @ Wih^T + bih ; gh = h @ Whh^T + bhh
    gemm_bt<<<dim3(N_NODES / 128, 6), 256, 0, stream>>>(m_b, wih_l, bih_l, gi, 768, 256);
    gemm_bt<<<dim3(N_NODES / 128, 6), 256, 0, stream>>>(h_b, whh_l, bhh_l, gh, 768, 256);
    // gate math, in-place bf16 h update
    gru_gates<<<(N_NODES * H_DIM) / 256, 256, 0, stream>>>(gi, gh, h_b);
  }

  readout_partial<<<B_GRAPHS * 8, 256, 0, stream>>>(h_b, part);
  readout_final<<<B_GRAPHS, 256, 0, stream>>>(part, out);

  (void)in_sizes; (void)n_in; (void)out_size;
}

// Round 5
// 667.782 us; speedup vs baseline: 1.4648x; 1.3669x over previous
//
#include <hip/hip_runtime.h>

// ---------------- problem constants ----------------
#define N_NODES 32768
#define E_EDGES 524288
#define F_IN    215
#define H_DIM   256
#define T_TYPES 8
#define L_LAYERS 3
#define B_GRAPHS 32
#define MAXN_   1024
#define NT_BINS (N_NODES * T_TYPES)   // 262144

typedef float  f32x4  __attribute__((ext_vector_type(4)));
typedef __bf16 bf16x8 __attribute__((ext_vector_type(8)));

__device__ __forceinline__ unsigned short f2bf(float f) {
  union { float f; unsigned u; } v; v.f = f;
  unsigned r = v.u + 0x7fffu + ((v.u >> 16) & 1u);
  return (unsigned short)(r >> 16);
}
__device__ __forceinline__ float bf2f(unsigned short h) {
  union { unsigned u; float f; } v; v.u = ((unsigned)h) << 16;
  return v.f;
}
__device__ __forceinline__ float bflo(unsigned u) { union { unsigned x; float f; } v; v.x = u << 16; return v.f; }
__device__ __forceinline__ float bfhi(unsigned u) { union { unsigned x; float f; } v; v.x = u & 0xffff0000u; return v.f; }

typedef const __attribute__((address_space(1))) unsigned int* gas_ptr;
typedef __attribute__((address_space(3))) unsigned int* las_ptr;
__device__ __forceinline__ void gload_lds16(const unsigned short* g, unsigned short* l) {
  __builtin_amdgcn_global_load_lds((gas_ptr)g, (las_ptr)l, 16, 0, 0);
}

// ---------------- ws layout (bytes) ----------------
// BIG region time-shared by liveness (stream order):
//   t0: counts(+0, 1MB) cursor(+1MB, 1MB) bsum(+2MB, 1KB)   [edge sort]
//   t1: xpad(+0, 16.8MB) wppad(+32MB, 131KB)                [input proj]
//   t2: h_alt(+48MB, 16.8MB)                                [layer ping-pong]
//   t3: part(+0, 256KB)                                     [readout]
static constexpr size_t OFF_BIG     = 0;            // 134217728
static constexpr size_t REL_CURSOR  = 1048576;
static constexpr size_t REL_BSUM    = 2097152;
static constexpr size_t REL_WPPAD   = 33554432;
static constexpr size_t REL_HALT    = 50331648;
static constexpr size_t OFF_H_B     = 134217728;    // 16777216   h bf16 (N,H)
static constexpr size_t OFF_M_B     = 150994944;    // 16777216   m bf16 (N,H)
static constexpr size_t OFF_WMB     = 167772160;    // 3145728    Wm bf16 (L,T,H,H) natural
static constexpr size_t OFF_WIH     = 170917888;    // 1179648    Wih bf16
static constexpr size_t OFF_WHH     = 172097536;    // 1179648    Whh bf16
static constexpr size_t OFF_OFFS    = 173277184;    // 1048832    seg offsets (NT+1)
static constexpr size_t OFF_SORTED  = 174326016;    // 1048576    src as ushort, sorted by (dst*8+t)
static constexpr size_t OFF_CNT     = 175374592;    // 524288     cnt16 (N,T) ushort
static constexpr size_t WS_REQUIRED = 175898880;    // 175.9 MB (proven safe)

// ---------------- edge preprocessing: counting sort by key=(dst*8+type) ----------------
__global__ void hist_kernel(const int* __restrict__ dst, const int* __restrict__ et,
                            int* __restrict__ cnt) {
  int e = blockIdx.x * 256 + threadIdx.x;
  atomicAdd(&cnt[dst[e] * T_TYPES + et[e]], 1);
}

__global__ void cvt_cnt16(const int* __restrict__ counts, unsigned short* __restrict__ c16) {
  int i = blockIdx.x * 256 + threadIdx.x;
  c16[i] = (unsigned short)counts[i];
}

__global__ __launch_bounds__(1024) void scan1(const int* __restrict__ cnt,
                                              int* __restrict__ offs,
                                              int* __restrict__ bsum) {
  __shared__ int wsum[16];
  const int t = threadIdx.x, lane = t & 63, wid = t >> 6;
  const int idx = blockIdx.x * 1024 + t;
  const int v = cnt[idx];
  int x = v;
  #pragma unroll
  for (int off = 1; off < 64; off <<= 1) {
    int u = __shfl_up(x, off, 64);
    if (lane >= off) x += u;
  }
  if (lane == 63) wsum[wid] = x;
  __syncthreads();
  int wbase = 0;
  for (int i = 0; i < wid; ++i) wbase += wsum[i];
  offs[idx] = wbase + x - v;
  if (t == 1023) bsum[blockIdx.x] = wbase + x;
}

__global__ __launch_bounds__(256) void scan2(int* __restrict__ bsum) {
  __shared__ int wsum[4];
  const int t = threadIdx.x, lane = t & 63, wid = t >> 6;
  const int v = bsum[t];
  int x = v;
  #pragma unroll
  for (int off = 1; off < 64; off <<= 1) {
    int u = __shfl_up(x, off, 64);
    if (lane >= off) x += u;
  }
  if (lane == 63) wsum[wid] = x;
  __syncthreads();
  int wbase = 0;
  for (int i = 0; i < wid; ++i) wbase += wsum[i];
  __syncthreads();
  bsum[t] = wbase + x - v;
}

__global__ __launch_bounds__(1024) void scan3(int* __restrict__ offs,
                                              const int* __restrict__ bsum,
                                              int* __restrict__ cursor) {
  const int idx = blockIdx.x * 1024 + threadIdx.x;
  const int o = offs[idx] + bsum[blockIdx.x];
  offs[idx] = o;
  cursor[idx] = o;
  if (idx == 0) offs[NT_BINS] = E_EDGES;
}

__global__ void reorder_kernel(const int* __restrict__ src, const int* __restrict__ dst,
                               const int* __restrict__ et, int* __restrict__ cursor,
                               unsigned short* __restrict__ sorted) {
  int e = blockIdx.x * 256 + threadIdx.x;
  int key = dst[e] * T_TYPES + et[e];
  int p = atomicAdd(&cursor[key], 1);
  sorted[p] = (unsigned short)src[e];
}

// ---------------- conversions ----------------
__global__ void cvt_f32_bf16(const float* __restrict__ in, unsigned short* __restrict__ out, int n) {
  int i = blockIdx.x * 256 + threadIdx.x;
  if (i < n) out[i] = f2bf(in[i]);
}

__global__ void pad_cvt(const float* __restrict__ in, unsigned short* __restrict__ out,
                        int rows, int cin) {
  int i = blockIdx.x * 256 + threadIdx.x;
  if (i >= rows * 256) return;
  int r = i >> 8, c = i & 255;
  out[i] = (c < cin) ? f2bf(in[(size_t)r * cin + c]) : (unsigned short)0;
}

// ---------------- GEMM: C(N x M) = A(N x K) @ W(M x K)^T (+bias), bf16 in/out ----------------
__global__ __launch_bounds__(256, 2) void gemm_bt(
    const unsigned short* __restrict__ A,
    const unsigned short* __restrict__ W,
    const float* __restrict__ bias,
    unsigned short* __restrict__ C,
    int M, int K) {
  __shared__ unsigned short As[128 * 32];
  __shared__ unsigned short Bs[128 * 32];
  const int tid = threadIdx.x;
  const int lane = tid & 63;
  const int wv = tid >> 6;
  const int lrow = lane & 15;
  const int lquad = lane >> 4;
  const int bm0 = blockIdx.x * 128;
  const int bn0 = blockIdx.y * 128;
  const int srow = wv * 16 + (lane >> 2);
  const int scol = (lane & 3) * 8;

  f32x4 acc[2][8] = {};

  for (int kt = 0; kt < K; kt += 32) {
    #pragma unroll
    for (int i = 0; i < 2; ++i) {
      const int row = srow + i * 64;
      gload_lds16(A + (size_t)(bm0 + row) * K + kt + scol, &As[row * 32 + scol]);
      gload_lds16(W + (size_t)(bn0 + row) * K + kt + scol, &Bs[row * 32 + scol]);
    }
    __syncthreads();
    bf16x8 af[2], bfr[8];
    #pragma unroll
    for (int mt = 0; mt < 2; ++mt)
      af[mt] = *(const bf16x8*)(&As[(wv * 32 + mt * 16 + lrow) * 32 + lquad * 8]);
    #pragma unroll
    for (int nt = 0; nt < 8; ++nt)
      bfr[nt] = *(const bf16x8*)(&Bs[(nt * 16 + lrow) * 32 + lquad * 8]);
    #pragma unroll
    for (int mt = 0; mt < 2; ++mt)
      #pragma unroll
      for (int nt = 0; nt < 8; ++nt)
        acc[mt][nt] = __builtin_amdgcn_mfma_f32_16x16x32_bf16(af[mt], bfr[nt], acc[mt][nt], 0, 0, 0);
    __syncthreads();
  }

  #pragma unroll
  for (int mt = 0; mt < 2; ++mt) {
    #pragma unroll
    for (int r = 0; r < 4; ++r) {
      const int grow = bm0 + wv * 32 + mt * 16 + lquad * 4 + r;
      #pragma unroll
      for (int nt = 0; nt < 8; ++nt) {
        const int gcol = bn0 + nt * 16 + lrow;
        float v = acc[mt][nt][r] + (bias ? bias[gcol] : 0.f);
        C[(size_t)grow * M + gcol] = f2bf(v);
      }
    }
  }
}

// ---------------- fused message GEMM (v2: 32-dst tiles, 36KB LDS -> 4 blk/CU) ----
// Per block: 32 dsts x 256 m-cols. Per type t: gather-sum h rows (unrolled x2)
// into LDS S_t (8 K-chunks, stride-40), then 8 MFMA K-steps vs Wm[l,t] staged
// via global_load_lds. Waves split rows(2) x cols(2). Epilogue folds
// sum_t cnt[dst,t]*bm[t,:]. S never touches HBM.
__global__ __launch_bounds__(256, 2) void msg_gemm(
    const int* __restrict__ offs, const unsigned short* __restrict__ sorted,
    const unsigned short* __restrict__ hb, const unsigned short* __restrict__ Wt_l,
    const unsigned short* __restrict__ cnt16, const float* __restrict__ bm_l,
    unsigned short* __restrict__ m) {
  __shared__ unsigned short Ss[8 * 32 * 40];   // 20 KB
  __shared__ unsigned short Bs[256 * 32];      // 16 KB; float bmS[2048] in epilogue
  const int tid = threadIdx.x;
  const int lane = tid & 63;
  const int wv = tid >> 6;
  const int lrow = lane & 15;
  const int lquad = lane >> 4;
  const int wrow = wv & 1;        // row half (16 dsts)
  const int wcol = wv >> 1;       // col half (128 cols)
  const int bm0 = blockIdx.x * 32;
  const int srow = wv * 16 + (lane >> 2);
  const int scol = (lane & 3) * 8;

  f32x4 acc[8] = {};

  for (int t = 0; t < T_TYPES; ++t) {
    // ---- phase A: build S_t (32 x 256) in LDS; 4 concurrent dsts/wave ----
    #pragma unroll
    for (int step = 0; step < 2; ++step) {
      const int dloc = wv * 8 + step * 4 + lquad;
      const int bin = (bm0 + dloc) * T_TYPES + t;
      const int beg = offs[bin], end = offs[bin + 1];
      float a[16];
      #pragma unroll
      for (int j = 0; j < 16; ++j) a[j] = 0.f;
      int e = beg;
      for (; e + 2 <= end; e += 2) {   // unroll x2: 4 dwordx4 in flight
        const int s0 = sorted[e], s1 = sorted[e + 1];
        const unsigned short* h0 = hb + (size_t)s0 * H_DIM + lrow * 16;
        const unsigned short* h1 = hb + (size_t)s1 * H_DIM + lrow * 16;
        const uint4 v0 = *(const uint4*)h0;
        const uint4 w0 = *(const uint4*)(h0 + 8);
        const uint4 v1 = *(const uint4*)h1;
        const uint4 w1 = *(const uint4*)(h1 + 8);
        a[0]  += bflo(v0.x) + bflo(v1.x); a[1]  += bfhi(v0.x) + bfhi(v1.x);
        a[2]  += bflo(v0.y) + bflo(v1.y); a[3]  += bfhi(v0.y) + bfhi(v1.y);
        a[4]  += bflo(v0.z) + bflo(v1.z); a[5]  += bfhi(v0.z) + bfhi(v1.z);
        a[6]  += bflo(v0.w) + bflo(v1.w); a[7]  += bfhi(v0.w) + bfhi(v1.w);
        a[8]  += bflo(w0.x) + bflo(w1.x); a[9]  += bfhi(w0.x) + bfhi(w1.x);
        a[10] += bflo(w0.y) + bflo(w1.y); a[11] += bfhi(w0.y) + bfhi(w1.y);
        a[12] += bflo(w0.z) + bflo(w1.z); a[13] += bfhi(w0.z) + bfhi(w1.z);
        a[14] += bflo(w0.w) + bflo(w1.w); a[15] += bfhi(w0.w) + bfhi(w1.w);
      }
      if (e < end) {
        const int s0 = sorted[e];
        const unsigned short* h0 = hb + (size_t)s0 * H_DIM + lrow * 16;
        const uint4 v0 = *(const uint4*)h0;
        const uint4 w0 = *(const uint4*)(h0 + 8);
        a[0]  += bflo(v0.x); a[1]  += bfhi(v0.x);
        a[2]  += bflo(v0.y); a[3]  += bfhi(v0.y);
        a[4]  += bflo(v0.z); a[5]  += bfhi(v0.z);
        a[6]  += bflo(v0.w); a[7]  += bfhi(v0.w);
        a[8]  += bflo(w0.x); a[9]  += bfhi(w0.x);
        a[10] += bflo(w0.y); a[11] += bfhi(w0.y);
        a[12] += bflo(w0.z); a[13] += bfhi(w0.z);
        a[14] += bflo(w0.w); a[15] += bfhi(w0.w);
      }
      union { unsigned short us[16]; uint4 q[2]; } ob;
      #pragma unroll
      for (int j = 0; j < 16; ++j) ob.us[j] = f2bf(a[j]);
      uint4* p = (uint4*)&Ss[(lrow >> 1) * 1280 + dloc * 40 + (lrow & 1) * 16];
      p[0] = ob.q[0];
      p[1] = ob.q[1];
    }
    __syncthreads();
    // ---- phase B: acc += S_t @ Wm[t]^T ----
    const unsigned short* Wt = Wt_l + (size_t)t * 256 * 256;
    for (int kc = 0; kc < 8; ++kc) {
      #pragma unroll
      for (int i = 0; i < 4; ++i) {
        const int j = srow + i * 64;
        gload_lds16(Wt + (size_t)j * 256 + kc * 32 + scol, &Bs[j * 32 + scol]);
      }
      __syncthreads();
      const bf16x8 af = *(const bf16x8*)(&Ss[kc * 1280 + (wrow * 16 + lrow) * 40 + lquad * 8]);
      #pragma unroll
      for (int nt = 0; nt < 8; ++nt) {
        const bf16x8 bfr = *(const bf16x8*)(&Bs[((wcol * 8 + nt) * 16 + lrow) * 32 + lquad * 8]);
        acc[nt] = __builtin_amdgcn_mfma_f32_16x16x32_bf16(af, bfr, acc[nt], 0, 0, 0);
      }
      __syncthreads();
    }
  }

  // ---- epilogue: m = acc + sum_t cnt[dst,t]*bm[t,:] ----
  float* bmS = (float*)Bs;   // Bs dead after final barrier
  for (int i = tid; i < T_TYPES * H_DIM; i += 256) bmS[i] = bm_l[i];
  __syncthreads();
  float cnt[4][8];
  #pragma unroll
  for (int r = 0; r < 4; ++r) {
    const int grow = bm0 + wrow * 16 + lquad * 4 + r;
    const uint4 cv = *(const uint4*)(cnt16 + (size_t)grow * T_TYPES);
    cnt[r][0] = (float)(cv.x & 0xffff); cnt[r][1] = (float)(cv.x >> 16);
    cnt[r][2] = (float)(cv.y & 0xffff); cnt[r][3] = (float)(cv.y >> 16);
    cnt[r][4] = (float)(cv.z & 0xffff); cnt[r][5] = (float)(cv.z >> 16);
    cnt[r][6] = (float)(cv.w & 0xffff); cnt[r][7] = (float)(cv.w >> 16);
  }
  #pragma unroll
  for (int nt = 0; nt < 8; ++nt) {
    const int gcol = wcol * 128 + nt * 16 + lrow;
    float bmv[8];
    #pragma unroll
    for (int t = 0; t < 8; ++t) bmv[t] = bmS[t * H_DIM + gcol];
    #pragma unroll
    for (int r = 0; r < 4; ++r) {
      const int grow = bm0 + wrow * 16 + lquad * 4 + r;
      float v = acc[nt][r];
      #pragma unroll
      for (int t = 0; t < 8; ++t) v += cnt[r][t] * bmv[t];
      m[(size_t)grow * H_DIM + gcol] = f2bf(v);
    }
  }
}

// ---------------- fused GRU: gi/gh GEMMs + gates, h ping-pong ----------------
// Block: 64 nodes x 64 h-cols. 6 GEMM col-groups {i_r,i_z,i_n,h_r,h_z,h_n}
// (rows g*256+c0.. of Wih/Whh). gi/gh never hit HBM.
__global__ __launch_bounds__(256, 2) void gru_fused(
    const unsigned short* __restrict__ mB,
    const unsigned short* __restrict__ hin,
    const unsigned short* __restrict__ wih_l,
    const unsigned short* __restrict__ whh_l,
    const float* __restrict__ bih_l,
    const float* __restrict__ bhh_l,
    unsigned short* __restrict__ hout) {
  __shared__ unsigned short Am[64 * 32];   // 4 KB
  __shared__ unsigned short Ah[64 * 32];   // 4 KB
  __shared__ unsigned short Bs[384 * 32];  // 24 KB
  const int tid = threadIdx.x;
  const int lane = tid & 63;
  const int wv = tid >> 6;
  const int lrow = lane & 15;
  const int lquad = lane >> 4;
  const int n0 = blockIdx.x * 64;
  const int c0 = blockIdx.y * 64;
  const int arow = tid >> 2;          // 0..63
  const int scol = (tid & 3) * 8;

  f32x4 acc[6][4] = {};

  for (int kt = 0; kt < 256; kt += 32) {
    gload_lds16(mB  + (size_t)(n0 + arow) * 256 + kt + scol, &Am[arow * 32 + scol]);
    gload_lds16(hin + (size_t)(n0 + arow) * 256 + kt + scol, &Ah[arow * 32 + scol]);
    #pragma unroll
    for (int g = 0; g < 3; ++g) {
      gload_lds16(wih_l + (size_t)(g * 256 + c0 + arow) * 256 + kt + scol,
                  &Bs[(g * 64 + arow) * 32 + scol]);
      gload_lds16(whh_l + (size_t)(g * 256 + c0 + arow) * 256 + kt + scol,
                  &Bs[((g + 3) * 64 + arow) * 32 + scol]);
    }
    __syncthreads();
    const bf16x8 am = *(const bf16x8*)(&Am[(wv * 16 + lrow) * 32 + lquad * 8]);
    const bf16x8 ah = *(const bf16x8*)(&Ah[(wv * 16 + lrow) * 32 + lquad * 8]);
    #pragma unroll
    for (int g = 0; g < 6; ++g) {
      const bf16x8 a = (g < 3) ? am : ah;
      #pragma unroll
      for (int nt = 0; nt < 4; ++nt) {
        const bf16x8 b = *(const bf16x8*)(&Bs[(g * 64 + nt * 16 + lrow) * 32 + lquad * 8]);
        acc[g][nt] = __builtin_amdgcn_mfma_f32_16x16x32_bf16(a, b, acc[g][nt], 0, 0, 0);
      }
    }
    __syncthreads();
  }

  #pragma unroll
  for (int nt = 0; nt < 4; ++nt) {
    const int c = c0 + nt * 16 + lrow;
    const float b_ir = bih_l[c], b_iz = bih_l[256 + c], b_in = bih_l[512 + c];
    const float b_hr = bhh_l[c], b_hz = bhh_l[256 + c], b_hn = bhh_l[512 + c];
    #pragma unroll
    for (int r = 0; r < 4; ++r) {
      const int node = n0 + wv * 16 + lquad * 4 + r;
      const float i_r = acc[0][nt][r] + b_ir;
      const float i_z = acc[1][nt][r] + b_iz;
      const float i_n = acc[2][nt][r] + b_in;
      const float h_r = acc[3][nt][r] + b_hr;
      const float h_z = acc[4][nt][r] + b_hz;
      const float h_n = acc[5][nt][r] + b_hn;
      const float rr = 1.f / (1.f + __expf(-(i_r + h_r)));
      const float zz = 1.f / (1.f + __expf(-(i_z + h_z)));
      const float nn = tanhf(i_n + rr * h_n);
      const float hp = bf2f(hin[(size_t)node * 256 + c]);
      hout[(size_t)node * 256 + c] = f2bf((1.f - zz) * nn + zz * hp);
    }
  }
}

// ---------------- readout ----------------
__global__ __launch_bounds__(256) void readout_partial(const unsigned short* __restrict__ hb,
                                                       float* __restrict__ part) {
  const int b = blockIdx.x >> 3;
  const int ch = blockIdx.x & 7;
  const int c = threadIdx.x;
  const unsigned short* base = hb + ((size_t)b * MAXN_ + ch * 128) * H_DIM + c;
  float s = 0.f;
  #pragma unroll 4
  for (int i = 0; i < 128; ++i) s += bf2f(base[(size_t)i * H_DIM]);
  part[(size_t)blockIdx.x * H_DIM + c] = s;
}

__global__ __launch_bounds__(256) void readout_final(const float* __restrict__ part,
                                                     float* __restrict__ out) {
  const int b = blockIdx.x;
  const int c = threadIdx.x;
  float s = 0.f;
  #pragma unroll
  for (int i = 0; i < 8; ++i) s += part[((size_t)b * 8 + i) * H_DIM + c];
  out[b * H_DIM + c] = s;
}

// ---------------- launch ----------------
extern "C" void kernel_launch(void* const* d_in, const int* in_sizes, int n_in,
                              void* d_out, int out_size, void* d_ws, size_t ws_size,
                              hipStream_t stream) {
  if (ws_size < WS_REQUIRED) return;  // diagnostic no-op guard

  const float* X   = (const float*)d_in[0];
  const int*   ei  = (const int*)d_in[1];
  const int*   et  = (const int*)d_in[2];
  const float* Wp  = (const float*)d_in[3];
  const float* bp  = (const float*)d_in[4];
  const float* Wm  = (const float*)d_in[5];
  const float* bm  = (const float*)d_in[6];
  const float* Wih = (const float*)d_in[7];
  const float* Whh = (const float*)d_in[8];
  const float* bih = (const float*)d_in[9];
  const float* bhh = (const float*)d_in[10];
  float* out = (float*)d_out;
  char* ws = (char*)d_ws;

  // BIG aliases (stream-ordered liveness)
  int*            counts = (int*)(ws + OFF_BIG);
  int*            cursor = (int*)(ws + OFF_BIG + REL_CURSOR);
  int*            bsum   = (int*)(ws + OFF_BIG + REL_BSUM);
  unsigned short* xpad   = (unsigned short*)(ws + OFF_BIG);
  unsigned short* wppad  = (unsigned short*)(ws + OFF_BIG + REL_WPPAD);
  unsigned short* h_alt  = (unsigned short*)(ws + OFF_BIG + REL_HALT);
  float*          part   = (float*)(ws + OFF_BIG);
  // persistent
  unsigned short* h_b    = (unsigned short*)(ws + OFF_H_B);
  unsigned short* m_b    = (unsigned short*)(ws + OFF_M_B);
  unsigned short* wmb    = (unsigned short*)(ws + OFF_WMB);
  unsigned short* wih_b  = (unsigned short*)(ws + OFF_WIH);
  unsigned short* whh_b  = (unsigned short*)(ws + OFF_WHH);
  int*            offs   = (int*)(ws + OFF_OFFS);
  unsigned short* sorted = (unsigned short*)(ws + OFF_SORTED);
  unsigned short* cnt16  = (unsigned short*)(ws + OFF_CNT);

  const int* src = ei;
  const int* dst = ei + E_EDGES;

  // ---- counting sort of edges by (dst*8 + type), once ----
  hipMemsetAsync(counts, 0, NT_BINS * sizeof(int), stream);
  hist_kernel<<<E_EDGES / 256, 256, 0, stream>>>(dst, et, counts);
  cvt_cnt16<<<NT_BINS / 256, 256, 0, stream>>>(counts, cnt16);
  scan1<<<NT_BINS / 1024, 1024, 0, stream>>>(counts, offs, bsum);
  scan2<<<1, 256, 0, stream>>>(bsum);
  scan3<<<NT_BINS / 1024, 1024, 0, stream>>>(offs, bsum, cursor);
  reorder_kernel<<<E_EDGES / 256, 256, 0, stream>>>(src, dst, et, cursor, sorted);

  // ---- weight/input conversion to bf16 ----
  pad_cvt<<<(N_NODES * 256) / 256, 256, 0, stream>>>(X, xpad, N_NODES, F_IN);
  pad_cvt<<<(256 * 256) / 256, 256, 0, stream>>>(Wp, wppad, 256, F_IN);
  cvt_f32_bf16<<<(L_LAYERS * T_TYPES * H_DIM * H_DIM) / 256, 256, 0, stream>>>(
      Wm, wmb, L_LAYERS * T_TYPES * H_DIM * H_DIM);
  cvt_f32_bf16<<<(L_LAYERS * 3 * H_DIM * H_DIM) / 256, 256, 0, stream>>>(Wih, wih_b, L_LAYERS * 3 * H_DIM * H_DIM);
  cvt_f32_bf16<<<(L_LAYERS * 3 * H_DIM * H_DIM) / 256, 256, 0, stream>>>(Whh, whh_b, L_LAYERS * 3 * H_DIM * H_DIM);

  // ---- input projection: h = X @ Wp^T + bp ----
  gemm_bt<<<dim3(N_NODES / 128, 2), 256, 0, stream>>>(xpad, wppad, bp, h_b, H_DIM, 256);

  for (int l = 0; l < L_LAYERS; ++l) {
    const unsigned short* wm_l  = wmb + (size_t)l * T_TYPES * H_DIM * H_DIM;
    const unsigned short* wih_l = wih_b + (size_t)l * 3 * H_DIM * H_DIM;
    const unsigned short* whh_l = whh_b + (size_t)l * 3 * H_DIM * H_DIM;
    const float* bm_l  = bm + (size_t)l * T_TYPES * H_DIM;
    const float* bih_l = bih + (size_t)l * 3 * H_DIM;
    const float* bhh_l = bhh + (size_t)l * 3 * H_DIM;

    unsigned short* h_cur = (l & 1) ? h_alt : h_b;
    unsigned short* h_nxt = (l & 1) ? h_b : h_alt;

    // fused: m = (scatter-sum_t h) @ Wm^T + cnt-weighted bm  (S stays in LDS)
    msg_gemm<<<N_NODES / 32, 256, 0, stream>>>(offs, sorted, h_cur, wm_l, cnt16, bm_l, m_b);
    // fused: h_nxt = GRU(m, h_cur)  (gi/gh stay in registers)
    gru_fused<<<dim3(N_NODES / 64, 4), 256, 0, stream>>>(
        m_b, h_cur, wih_l, whh_l, bih_l, bhh_l, h_nxt);
  }

  // h after 3 layers is in h_alt (l=2 writes h_alt); part at BIG+0 is disjoint
  readout_partial<<<B_GRAPHS * 8, 256, 0, stream>>>(h_alt, part);
  readout_final<<<B_GRAPHS, 256, 0, stream>>>(part, out);

  (void)in_sizes; (void)n_in; (void)out_size;
}